// Round 10
// baseline (184.386 us; speedup 1.0000x reference)
//
#include <hip/hip_runtime.h>
#include <hip/hip_bf16.h>

typedef __hip_bfloat16 bf16;
typedef short bf16x8 __attribute__((ext_vector_type(8)));
typedef float f32x4 __attribute__((ext_vector_type(4)));

#define NGRAPH 16
#define QSCALE 0.17677669529663687f
#define VT_LD 8192  // V^T leading dim: 16 graphs x 512 slots

// load 8 consecutive f32 and convert to a bf16x8 A/B fragment
__device__ __forceinline__ bf16x8 ldcvt8(const float* p) {
  float4 u = *(const float4*)p, v = *(const float4*)(p + 4);
  __align__(16) bf16 tmp[8];
  tmp[0] = __float2bfloat16(u.x); tmp[1] = __float2bfloat16(u.y);
  tmp[2] = __float2bfloat16(u.z); tmp[3] = __float2bfloat16(u.w);
  tmp[4] = __float2bfloat16(v.x); tmp[5] = __float2bfloat16(v.y);
  tmp[6] = __float2bfloat16(v.z); tmp[7] = __float2bfloat16(v.w);
  return *(const bf16x8*)tmp;
}

// ---------------- K1: W transposes (LDS-tiled, coalesced) + graph offsets ----------------
__global__ __launch_bounds__(256) void k_pre(const float* __restrict__ Wqkv,
                                             const float* __restrict__ Wout,
                                             const int* __restrict__ batch,
                                             bf16* __restrict__ Wqkv_t,
                                             bf16* __restrict__ Wout_t,
                                             int* __restrict__ offs, int N) {
  __shared__ float ld[64][65];
  int bid = blockIdx.x, t = threadIdx.x;
  int c = t & 63, r0 = t >> 6;
  if (bid < 48) {  // Wqkv [256][768] -> Wqkv_t [768][256]
    int k0 = (bid & 3) * 64, n0 = (bid >> 2) * 64;
    #pragma unroll
    for (int r = r0; r < 64; r += 4) ld[r][c] = Wqkv[(size_t)(k0 + r) * 768 + n0 + c];
    __syncthreads();
    #pragma unroll
    for (int r = r0; r < 64; r += 4)
      Wqkv_t[(size_t)(n0 + r) * 256 + k0 + c] = __float2bfloat16(ld[c][r]);
  } else if (bid < 64) {  // Wout [256][256] -> Wout_t [256][256]
    int b2 = bid - 48;
    int k0 = (b2 & 3) * 64, n0 = (b2 >> 2) * 64;
    #pragma unroll
    for (int r = r0; r < 64; r += 4) ld[r][c] = Wout[(size_t)(k0 + r) * 256 + n0 + c];
    __syncthreads();
    #pragma unroll
    for (int r = r0; r < 64; r += 4)
      Wout_t[(size_t)(n0 + r) * 256 + k0 + c] = __float2bfloat16(ld[c][r]);
  } else {  // offsets from sorted batch ids
    for (int i = t; i < N; i += 256) {
      if (i == 0) { offs[0] = 0; offs[NGRAPH] = N; }
      else if (batch[i] != batch[i - 1]) offs[batch[i]] = i;
    }
  }
}

// ---------------- K2: QKV GEMM (x f32 direct-convert), LDS-free MFMA, + V^T ----------------
__global__ __launch_bounds__(256) void k_gemm(const float* __restrict__ x,
                                              const bf16* __restrict__ Wqkv_t,
                                              const int* __restrict__ batch,
                                              const int* __restrict__ offs,
                                              bf16* __restrict__ QKVb,
                                              bf16* __restrict__ VT,
                                              int N, int MBm) {
  __shared__ float tr[64][65];
  __shared__ int rowcol[64];
  int t = threadIdx.x, bid = blockIdx.x;
  int w = t >> 6, l = t & 63, fr = l & 15, fq = l >> 4;
  int m0 = (bid % MBm) * 64, n0 = (bid / MBm) * 64;
  bool isV = (n0 >= 512);
  if (isV && t < 64) {
    int m = m0 + t; if (m > N - 1) m = N - 1;
    int b = batch[m];
    rowcol[t] = b * 512 + (m - offs[b]);
  }
  int arow = m0 + w * 16 + fr; if (arow > N - 1) arow = N - 1;
  bf16x8 af[8];
  #pragma unroll
  for (int kt = 0; kt < 8; ++kt)
    af[kt] = ldcvt8(x + (size_t)arow * 256 + kt * 32 + fq * 8);
  f32x4 acc[4];
  #pragma unroll
  for (int nt = 0; nt < 4; ++nt) acc[nt] = (f32x4){0.f, 0.f, 0.f, 0.f};
  #pragma unroll
  for (int nt = 0; nt < 4; ++nt) {
    int brow = n0 + nt * 16 + fr;
    #pragma unroll
    for (int kt = 0; kt < 8; ++kt) {
      bf16x8 bf_ = *(const bf16x8*)(Wqkv_t + (size_t)brow * 256 + kt * 32 + fq * 8);
      acc[nt] = __builtin_amdgcn_mfma_f32_16x16x32_bf16(af[kt], bf_, acc[nt], 0, 0, 0);
    }
  }
  #pragma unroll
  for (int nt = 0; nt < 4; ++nt) {
    int col = n0 + nt * 16 + fr;
    float sc = (col < 256) ? QSCALE : 1.f;
    #pragma unroll
    for (int rr = 0; rr < 4; ++rr) {
      int m = m0 + w * 16 + fq * 4 + rr;
      if (m < N) QKVb[(size_t)m * 768 + col] = __float2bfloat16(acc[nt][rr] * sc);
    }
  }
  if (isV) {
    #pragma unroll
    for (int nt = 0; nt < 4; ++nt)
      #pragma unroll
      for (int rr = 0; rr < 4; ++rr)
        tr[nt * 16 + fr][w * 16 + fq * 4 + rr] = acc[nt][rr];
    __syncthreads();
    int c = t >> 2, r0 = (t & 3) * 16;
    int dg = (n0 - 512) + c;
    #pragma unroll
    for (int i = 0; i < 16; ++i) {
      int r = r0 + i;
      VT[(size_t)dg * VT_LD + rowcol[r]] = __float2bfloat16(tr[c][r]);
    }
  }
}

// ---------------- K3: fused MFMA flash attention + in-loop RoPE bias, j-split x2 --------
// block = (q-tile 16, graph, z: head-half x j-chunk). 4 waves, wave = one head.
// No-max softmax => partials over disjoint j-ranges are ADDITIVE: each chunk writes
// unnormalized f32 O and l; k_out_ln sums and divides.
__global__ __launch_bounds__(256) void k_attn(const float* __restrict__ pos,
                                              const float* __restrict__ freqs,
                                              const float* __restrict__ Wrope,
                                              const bf16* __restrict__ QKVb,
                                              const bf16* __restrict__ VT,
                                              const int* __restrict__ offs,
                                              float* __restrict__ Op,
                                              float* __restrict__ lp, int N) {
  __shared__ float Sb[2][4][16][36];            // stride 36 -> <=2-way banks (free)
  __shared__ __align__(16) bf16 Pt[4][16][40];
  int b = blockIdx.y;
  int zc = blockIdx.z;
  int hbase = (zc & 1) * 4;
  int jc = zc >> 1;                              // j-chunk 0/1
  int off = offs[b], n = offs[b + 1] - off;
  int q0 = blockIdx.x * 16;
  if (q0 >= n) return;
  int t = threadIdx.x, w = t >> 6, l = t & 63, fr = l & 15, fq = l >> 4;
  int h = hbase + w;
  const bf16* Kb = QKVb + (size_t)off * 768 + 256 + h * 32 + fq * 8;
  const bf16* Vb = VT + (size_t)(h * 32 + fr) * VT_LD + b * 512 + fq * 8;
  int qrow = q0 + fr; bool qv = qrow < n;
  bf16x8 aq = *(const bf16x8*)(QKVb + (size_t)(qv ? off + qrow : off) * 768 + h * 32 + fq * 8);
  if (!qv) aq = (bf16x8){0, 0, 0, 0, 0, 0, 0, 0};

  // bias-producer role: thread owns pairs (q=bq, j=bj) and (q=bq+8, j=bj)
  int bq = t >> 5, bj = t & 31;
  float qpx[2], qpy[2], qpz[2]; bool bqv[2];
  #pragma unroll
  for (int e = 0; e < 2; ++e) {
    int qq = q0 + bq + 8 * e; bqv[e] = qq < n;
    int a = (bqv[e] ? off + qq : off) * 3;
    qpx[e] = pos[a]; qpy[e] = pos[a + 1]; qpz[e] = pos[a + 2];
  }

  f32x4 Oa[2];
  Oa[0] = (f32x4){0.f, 0.f, 0.f, 0.f}; Oa[1] = (f32x4){0.f, 0.f, 0.f, 0.f};
  float lacc[4] = {0.f, 0.f, 0.f, 0.f};
  int jtiles = (n + 31) >> 5;
  int jt0 = (jtiles * jc) >> 1, jt1 = (jtiles * (jc + 1)) >> 1;

#define PRODUCE(JT, BUF) do {                                                     \
    int _jg = (JT) * 32 + bj; bool _vj = _jg < n;                                 \
    int _a = (_vj ? off + _jg : off) * 3;                                         \
    float _jx = pos[_a], _jy = pos[_a + 1], _jz = pos[_a + 2];                    \
    _Pragma("unroll")                                                             \
    for (int _e = 0; _e < 2; ++_e) {                                              \
      float _b0 = 0.f, _b1 = 0.f, _b2 = 0.f, _b3 = 0.f;                           \
      if (_vj && bqv[_e]) {                                                       \
        float _dx = qpx[_e] - _jx, _dy = qpy[_e] - _jy, _dz = qpz[_e] - _jz;      \
        float _d = sqrtf(_dx * _dx + _dy * _dy + _dz * _dz);                      \
        _Pragma("unroll")                                                         \
        for (int _r = 0; _r < 16; ++_r) {                                         \
          float _cv = __cosf(_d * fabsf(freqs[_r]));                              \
          _b0 += _cv * Wrope[_r * 8 + hbase + 0];                                 \
          _b1 += _cv * Wrope[_r * 8 + hbase + 1];                                 \
          _b2 += _cv * Wrope[_r * 8 + hbase + 2];                                 \
          _b3 += _cv * Wrope[_r * 8 + hbase + 3];                                 \
        }                                                                         \
      }                                                                           \
      int _qi = bq + 8 * _e;                                                      \
      Sb[BUF][0][_qi][bj] = _vj ? _b0 : -1e30f;                                   \
      Sb[BUF][1][_qi][bj] = _vj ? _b1 : -1e30f;                                   \
      Sb[BUF][2][_qi][bj] = _vj ? _b2 : -1e30f;                                   \
      Sb[BUF][3][_qi][bj] = _vj ? _b3 : -1e30f;                                   \
    }                                                                             \
  } while (0)

#define LOADT(JT, K0_, K1_, V0_, V1_) do {                                        \
    int _jt = (JT); int _k0 = _jt * 32 + fr, _k1 = _k0 + 16;                      \
    K0_ = *(const bf16x8*)(Kb + (size_t)((_k0 < n) ? _k0 : 0) * 768);             \
    K1_ = *(const bf16x8*)(Kb + (size_t)((_k1 < n) ? _k1 : 0) * 768);             \
    V0_ = *(const bf16x8*)(Vb + _jt * 32);                                        \
    V1_ = *(const bf16x8*)(Vb + (size_t)16 * VT_LD + _jt * 32);                   \
  } while (0)

  bf16x8 ck0, ck1, cv0, cv1;
  LOADT(jt0, ck0, ck1, cv0, cv1);
  PRODUCE(jt0, 0);
  __syncthreads();
  for (int jt = jt0; jt < jt1; ++jt) {
    int par = (jt - jt0) & 1;
    bf16x8 nk0, nk1, nv0, nv1;
    if (jt + 1 < jt1) {
      LOADT(jt + 1, nk0, nk1, nv0, nv1);     // global prefetch issued early
      PRODUCE(jt + 1, par ^ 1);              // VALU cos work into other buffer
    }
    f32x4 z = {0.f, 0.f, 0.f, 0.f};
    f32x4 S0 = __builtin_amdgcn_mfma_f32_16x16x32_bf16(aq, ck0, z, 0, 0, 0);
    f32x4 S1 = __builtin_amdgcn_mfma_f32_16x16x32_bf16(aq, ck1, z, 0, 0, 0);
    #pragma unroll
    for (int k = 0; k < 8; ++k) {
      int jti = k >> 2, rr = k & 3;
      float s = (jti ? S1[rr] : S0[rr]) + Sb[par][w][fq * 4 + rr][jti * 16 + fr];
      float p = __expf(s);
      lacc[rr] += p;
      Pt[w][fq * 4 + rr][jti * 16 + fr] = __float2bfloat16(p);
    }
    bf16x8 ap = *(const bf16x8*)&Pt[w][fr][fq * 8];
    Oa[0] = __builtin_amdgcn_mfma_f32_16x16x32_bf16(ap, cv0, Oa[0], 0, 0, 0);
    Oa[1] = __builtin_amdgcn_mfma_f32_16x16x32_bf16(ap, cv1, Oa[1], 0, 0, 0);
    ck0 = nk0; ck1 = nk1; cv0 = nv0; cv1 = nv1;
    __syncthreads();
  }
#undef LOADT
#undef PRODUCE
  #pragma unroll
  for (int rr = 0; rr < 4; ++rr) {
    #pragma unroll
    for (int m2 = 1; m2 <= 8; m2 <<= 1) lacc[rr] += __shfl_xor(lacc[rr], m2);
  }
  float* Opc = Op + (size_t)jc * N * 256;
  float* lpc = lp + (size_t)jc * N * 8;
  #pragma unroll
  for (int rr = 0; rr < 4; ++rr) {
    int row = q0 + fq * 4 + rr;
    if (row < n) {
      #pragma unroll
      for (int dh = 0; dh < 2; ++dh)
        Opc[(size_t)(off + row) * 256 + h * 32 + dh * 16 + fr] = Oa[dh][rr];
      if (fr == 0) lpc[(size_t)(off + row) * 8 + h] = lacc[rr];
    }
  }
}

// ---------------- K4: combine j-partials + out-proj GEMM + residual + LN ----------------
__global__ __launch_bounds__(256) void k_out_ln(const float* __restrict__ Op,
                                                const float* __restrict__ lp,
                                                const bf16* __restrict__ Bt,
                                                const float* __restrict__ x,
                                                const float* __restrict__ gamma,
                                                const float* __restrict__ beta,
                                                float* __restrict__ out, int M) {
  __shared__ float ps[4][16], pss[4][16];
  int t = threadIdx.x, w = t >> 6, l = t & 63, fr = l & 15, fq = l >> 4;
  int m0 = blockIdx.x * 16;
  int arow = m0 + fr; if (arow > M - 1) arow = M - 1;
  const float* Op0 = Op;
  const float* Op1 = Op + (size_t)M * 256;
  // per-row l (8 heads) = sum of two j-chunk partials
  float linv[8];
  {
    float4 a0 = *(const float4*)(lp + (size_t)arow * 8);
    float4 a1 = *(const float4*)(lp + (size_t)arow * 8 + 4);
    float4 b0 = *(const float4*)(lp + (size_t)(M + arow) * 8);
    float4 b1 = *(const float4*)(lp + (size_t)(M + arow) * 8 + 4);
    linv[0] = 1.f / (a0.x + b0.x); linv[1] = 1.f / (a0.y + b0.y);
    linv[2] = 1.f / (a0.z + b0.z); linv[3] = 1.f / (a0.w + b0.w);
    linv[4] = 1.f / (a1.x + b1.x); linv[5] = 1.f / (a1.y + b1.y);
    linv[6] = 1.f / (a1.z + b1.z); linv[7] = 1.f / (a1.w + b1.w);
  }
  bf16x8 af[8];
  #pragma unroll
  for (int kt = 0; kt < 8; ++kt) {  // head h == kt (32 d per head)
    size_t o = (size_t)arow * 256 + kt * 32 + fq * 8;
    float4 u0 = *(const float4*)(Op0 + o),     v0 = *(const float4*)(Op0 + o + 4);
    float4 u1 = *(const float4*)(Op1 + o),     v1 = *(const float4*)(Op1 + o + 4);
    float li = linv[kt];
    __align__(16) bf16 tmp[8];
    tmp[0] = __float2bfloat16((u0.x + u1.x) * li);
    tmp[1] = __float2bfloat16((u0.y + u1.y) * li);
    tmp[2] = __float2bfloat16((u0.z + u1.z) * li);
    tmp[3] = __float2bfloat16((u0.w + u1.w) * li);
    tmp[4] = __float2bfloat16((v0.x + v1.x) * li);
    tmp[5] = __float2bfloat16((v0.y + v1.y) * li);
    tmp[6] = __float2bfloat16((v0.z + v1.z) * li);
    tmp[7] = __float2bfloat16((v0.w + v1.w) * li);
    af[kt] = *(const bf16x8*)tmp;
  }
  f32x4 acc[4];
  #pragma unroll
  for (int nt = 0; nt < 4; ++nt) {
    acc[nt] = (f32x4){0.f, 0.f, 0.f, 0.f};
    int brow = w * 64 + nt * 16 + fr;
    #pragma unroll
    for (int kt = 0; kt < 8; ++kt) {
      bf16x8 bf_ = *(const bf16x8*)(Bt + (size_t)brow * 256 + kt * 32 + fq * 8);
      acc[nt] = __builtin_amdgcn_mfma_f32_16x16x32_bf16(af[kt], bf_, acc[nt], 0, 0, 0);
    }
  }
  float y[4][4];
  #pragma unroll
  for (int rr = 0; rr < 4; ++rr) {
    int row = m0 + fq * 4 + rr;
    int rc = (row < M) ? row : (M - 1);
    float s = 0.f, ss = 0.f;
    #pragma unroll
    for (int nt = 0; nt < 4; ++nt) {
      float v = acc[nt][rr] + x[(size_t)rc * 256 + w * 64 + nt * 16 + fr];
      y[rr][nt] = v; s += v; ss += v * v;
    }
    #pragma unroll
    for (int m2 = 1; m2 <= 8; m2 <<= 1) { s += __shfl_xor(s, m2); ss += __shfl_xor(ss, m2); }
    if (fr == 0) { ps[w][fq * 4 + rr] = s; pss[w][fq * 4 + rr] = ss; }
  }
  __syncthreads();
  #pragma unroll
  for (int rr = 0; rr < 4; ++rr) {
    int row = m0 + fq * 4 + rr;
    int ri = fq * 4 + rr;
    float s = ps[0][ri] + ps[1][ri] + ps[2][ri] + ps[3][ri];
    float ss = pss[0][ri] + pss[1][ri] + pss[2][ri] + pss[3][ri];
    float mean = s * (1.f / 256.f);
    float var = ss * (1.f / 256.f) - mean * mean;
    float rstd = rsqrtf(var + 1e-5f);
    if (row < M) {
      #pragma unroll
      for (int nt = 0; nt < 4; ++nt) {
        int col = w * 64 + nt * 16 + fr;
        out[(size_t)row * 256 + col] = gamma[col] * (y[rr][nt] - mean) * rstd + beta[col];
      }
    }
  }
}

extern "C" void kernel_launch(void* const* d_in, const int* in_sizes, int n_in,
                              void* d_out, int out_size, void* d_ws, size_t ws_size,
                              hipStream_t stream) {
  (void)n_in; (void)out_size; (void)ws_size;
  const float* x     = (const float*)d_in[0];
  const float* pos   = (const float*)d_in[1];
  const int*   batch = (const int*)d_in[2];
  const float* Wqkv  = (const float*)d_in[3];
  const float* Wout  = (const float*)d_in[4];
  const float* freqs = (const float*)d_in[5];
  const float* Wrope = (const float*)d_in[6];
  const float* gamma = (const float*)d_in[7];
  const float* beta  = (const float*)d_in[8];
  float* out = (float*)d_out;

  int N = in_sizes[0] / 256;  // 6137

  char* base = (char*)d_ws;
  int*   offs   = (int*)base;                   // @0
  bf16*  QKVb   = (bf16*)(base + 1024);         // N*768*2  = 9,426,432
  bf16*  VT     = (bf16*)(base + 9427456);      // 4,194,304
  bf16*  Wqkv_t = (bf16*)(base + 13621760);     // 393,216
  bf16*  Wout_t = (bf16*)(base + 14014976);     // 131,072
  float* Op     = (float*)(base + 14146048);    // 2 x N*256*4 = 12,568,576
  float* lp     = (float*)(base + 26714624);    // 2 x N*8*4   = 392,768

  int MBm = (N + 63) / 64;  // 96
  k_pre<<<65, 256, 0, stream>>>(Wqkv, Wout, batch, Wqkv_t, Wout_t, offs, N);
  k_gemm<<<MBm * 12, 256, 0, stream>>>(x, Wqkv_t, batch, offs, QKVb, VT, N, MBm);
  k_attn<<<dim3(32, NGRAPH, 4), 256, 0, stream>>>(pos, freqs, Wrope, QKVb, VT, offs, Op, lp, N);
  k_out_ln<<<(N + 15) / 16, 256, 0, stream>>>(Op, lp, Wout_t, x, gamma, beta, out, N);
}

// Round 11
// 178.477 us; speedup vs baseline: 1.0331x; 1.0331x over previous
//
#include <hip/hip_runtime.h>
#include <hip/hip_bf16.h>

typedef __hip_bfloat16 bf16;
typedef short bf16x8 __attribute__((ext_vector_type(8)));
typedef float f32x4 __attribute__((ext_vector_type(4)));

#define NGRAPH 16
#define QSCALE 0.17677669529663687f
#define VT_LD 8192  // V^T leading dim: 16 graphs x 512 slots

struct __align__(16) bf8x { bf16 v[8]; };

__device__ __forceinline__ float b2f(bf16 v) { return __bfloat162float(v); }

// load 8 consecutive f32 and convert to a bf16x8 A/B fragment
__device__ __forceinline__ bf16x8 ldcvt8(const float* p) {
  float4 u = *(const float4*)p, v = *(const float4*)(p + 4);
  __align__(16) bf16 tmp[8];
  tmp[0] = __float2bfloat16(u.x); tmp[1] = __float2bfloat16(u.y);
  tmp[2] = __float2bfloat16(u.z); tmp[3] = __float2bfloat16(u.w);
  tmp[4] = __float2bfloat16(v.x); tmp[5] = __float2bfloat16(v.y);
  tmp[6] = __float2bfloat16(v.z); tmp[7] = __float2bfloat16(v.w);
  return *(const bf16x8*)tmp;
}

// ---------------- K1: W transposes (LDS-tiled, coalesced) + graph offsets ----------------
__global__ __launch_bounds__(256) void k_pre(const float* __restrict__ Wqkv,
                                             const float* __restrict__ Wout,
                                             const int* __restrict__ batch,
                                             bf16* __restrict__ Wqkv_t,
                                             bf16* __restrict__ Wout_t,
                                             int* __restrict__ offs, int N) {
  __shared__ float ld[64][65];
  int bid = blockIdx.x, t = threadIdx.x;
  int c = t & 63, r0 = t >> 6;
  if (bid < 48) {  // Wqkv [256][768] -> Wqkv_t [768][256]
    int k0 = (bid & 3) * 64, n0 = (bid >> 2) * 64;
    #pragma unroll
    for (int r = r0; r < 64; r += 4) ld[r][c] = Wqkv[(size_t)(k0 + r) * 768 + n0 + c];
    __syncthreads();
    #pragma unroll
    for (int r = r0; r < 64; r += 4)
      Wqkv_t[(size_t)(n0 + r) * 256 + k0 + c] = __float2bfloat16(ld[c][r]);
  } else if (bid < 64) {  // Wout [256][256] -> Wout_t [256][256]
    int b2 = bid - 48;
    int k0 = (b2 & 3) * 64, n0 = (b2 >> 2) * 64;
    #pragma unroll
    for (int r = r0; r < 64; r += 4) ld[r][c] = Wout[(size_t)(k0 + r) * 256 + n0 + c];
    __syncthreads();
    #pragma unroll
    for (int r = r0; r < 64; r += 4)
      Wout_t[(size_t)(n0 + r) * 256 + k0 + c] = __float2bfloat16(ld[c][r]);
  } else {  // offsets from sorted batch ids
    for (int i = t; i < N; i += 256) {
      if (i == 0) { offs[0] = 0; offs[NGRAPH] = N; }
      else if (batch[i] != batch[i - 1]) offs[batch[i]] = i;
    }
  }
}

// ---------------- K2: QKV GEMM, A-fragment reused across Q/K/V groups + V^T ----------------
// grid (MBm, 4): block does 64 rows x (three 64-col groups: Q|K|V at n0, 256+n0, 512+n0)
__global__ __launch_bounds__(256) void k_gemm(const float* __restrict__ x,
                                              const bf16* __restrict__ Wqkv_t,
                                              const int* __restrict__ batch,
                                              const int* __restrict__ offs,
                                              bf16* __restrict__ QKVb,
                                              bf16* __restrict__ VT, int N) {
  __shared__ float tr[64][65];
  __shared__ int rowcol[64];
  int t = threadIdx.x;
  int w = t >> 6, l = t & 63, fr = l & 15, fq = l >> 4;
  int m0 = blockIdx.x * 64, n0 = blockIdx.y * 64;
  if (t < 64) {
    int m = m0 + t; if (m > N - 1) m = N - 1;
    int b = batch[m];
    rowcol[t] = b * 512 + (m - offs[b]);
  }
  int arow = m0 + w * 16 + fr; if (arow > N - 1) arow = N - 1;
  bf16x8 af[8];
  #pragma unroll
  for (int kt = 0; kt < 8; ++kt)
    af[kt] = ldcvt8(x + (size_t)arow * 256 + kt * 32 + fq * 8);
  #pragma unroll
  for (int p = 0; p < 3; ++p) {
    f32x4 acc[4];
    #pragma unroll
    for (int nt = 0; nt < 4; ++nt) {
      acc[nt] = (f32x4){0.f, 0.f, 0.f, 0.f};
      int brow = p * 256 + n0 + nt * 16 + fr;
      #pragma unroll
      for (int kt = 0; kt < 8; ++kt) {
        bf16x8 bf_ = *(const bf16x8*)(Wqkv_t + (size_t)brow * 256 + kt * 32 + fq * 8);
        acc[nt] = __builtin_amdgcn_mfma_f32_16x16x32_bf16(af[kt], bf_, acc[nt], 0, 0, 0);
      }
    }
    float sc = (p == 0) ? QSCALE : 1.f;
    #pragma unroll
    for (int nt = 0; nt < 4; ++nt) {
      int col = p * 256 + n0 + nt * 16 + fr;
      #pragma unroll
      for (int rr = 0; rr < 4; ++rr) {
        int m = m0 + w * 16 + fq * 4 + rr;
        if (m < N) QKVb[(size_t)m * 768 + col] = __float2bfloat16(acc[nt][rr] * sc);
      }
    }
    if (p == 2) {  // V^T side output
      #pragma unroll
      for (int nt = 0; nt < 4; ++nt)
        #pragma unroll
        for (int rr = 0; rr < 4; ++rr)
          tr[nt * 16 + fr][w * 16 + fq * 4 + rr] = acc[nt][rr];
      __syncthreads();
      int c = t >> 2, r0 = (t & 3) * 16;
      int dg = n0 + c;  // head*32 + d
      #pragma unroll
      for (int i = 0; i < 16; ++i) {
        int r = r0 + i;
        VT[(size_t)dg * VT_LD + rowcol[r]] = __float2bfloat16(tr[c][r]);
      }
    }
  }
}

// ---------------- K3: fused MFMA flash attention; bias via LDS distance table ----------------
// block = (q-tile 16, graph, j-chunk). 4 waves, wave = heads {w, w+4}.
// bias_h(d) = sum_r W[r,h] cos(d f_r) tabulated per block: T[384][8] bf16, d step 1/8,
// lerped per pair -> all transcendentals & projection FMAs leave the hot loop.
__global__ __launch_bounds__(256) void k_attn(const float* __restrict__ pos,
                                              const float* __restrict__ freqs,
                                              const float* __restrict__ Wrope,
                                              const bf16* __restrict__ QKVb,
                                              const bf16* __restrict__ VT,
                                              const int* __restrict__ offs,
                                              float* __restrict__ Op,
                                              float* __restrict__ lp, int N) {
  __shared__ __align__(16) bf16 Tg[384][8];        // bias table [d_idx][head]
  __shared__ __align__(16) bf16 Sbf[2][8][64][8];  // bias tiles in MFMA C-frag order
  __shared__ __align__(16) bf16 Pt[4][16][40];     // per-wave P C->A transform
  int b = blockIdx.y, jc = blockIdx.z;
  int off = offs[b], n = offs[b + 1] - off;
  int q0 = blockIdx.x * 16;
  if (q0 >= n) return;
  int t = threadIdx.x, w = t >> 6, l = t & 63, fr = l & 15, fq = l >> 4;

  // ---- build bias table (once per block) ----
  for (int i = t; i < 384; i += 256) {
    float d = i * 0.125f;
    float a[8];
    #pragma unroll
    for (int h = 0; h < 8; ++h) a[h] = 0.f;
    #pragma unroll
    for (int r = 0; r < 16; ++r) {
      float cv = __cosf(d * fabsf(freqs[r]));
      #pragma unroll
      for (int h = 0; h < 8; ++h) a[h] += cv * Wrope[r * 8 + h];
    }
    __align__(16) bf16 row[8];
    #pragma unroll
    for (int h = 0; h < 8; ++h) row[h] = __float2bfloat16(a[h]);
    *(bf16x8*)&Tg[i][0] = *(const bf16x8*)row;
  }

  int h0 = w, h1 = w + 4;
  const bf16* Kb0 = QKVb + (size_t)off * 768 + 256 + h0 * 32 + fq * 8;
  const bf16* Kb1 = QKVb + (size_t)off * 768 + 256 + h1 * 32 + fq * 8;
  const bf16* Vb0 = VT + (size_t)(h0 * 32 + fr) * VT_LD + b * 512 + fq * 8;
  const bf16* Vb1 = VT + (size_t)(h1 * 32 + fr) * VT_LD + b * 512 + fq * 8;
  int qrow = q0 + fr; bool qv = qrow < n;
  size_t qoff = (size_t)(qv ? off + qrow : off) * 768 + fq * 8;
  bf16x8 aq[2];
  aq[0] = *(const bf16x8*)(QKVb + qoff + h0 * 32);
  aq[1] = *(const bf16x8*)(QKVb + qoff + h1 * 32);
  if (!qv) { aq[0] = (bf16x8){0,0,0,0,0,0,0,0}; aq[1] = aq[0]; }

  // bias producer role: thread owns pairs (q=bq, j=bj) and (q=bq+8, j=bj)
  int bq = t >> 5, bj = t & 31;
  float qpx[2], qpy[2], qpz[2]; bool bqv[2];
  #pragma unroll
  for (int e = 0; e < 2; ++e) {
    int qq = q0 + bq + 8 * e; bqv[e] = qq < n;
    int a = (bqv[e] ? off + qq : off) * 3;
    qpx[e] = pos[a]; qpy[e] = pos[a + 1]; qpz[e] = pos[a + 2];
  }

  f32x4 Oa[2][2];
  Oa[0][0] = (f32x4){0.f,0.f,0.f,0.f}; Oa[0][1] = Oa[0][0];
  Oa[1][0] = Oa[0][0];                 Oa[1][1] = Oa[0][0];
  float lacc[2][4] = {{0.f,0.f,0.f,0.f},{0.f,0.f,0.f,0.f}};
  int jtiles = (n + 31) >> 5;
  int jt0 = (jtiles * jc) >> 1, jt1 = (jtiles * (jc + 1)) >> 1;

  auto produce = [&](int JT, int BUF) {
    int jg = JT * 32 + bj; bool vj = jg < n;
    int a = (vj ? off + jg : off) * 3;
    float jx = pos[a], jy = pos[a + 1], jz = pos[a + 2];
    #pragma unroll
    for (int e = 0; e < 2; ++e) {
      int q = bq + 8 * e;
      int L = (q >> 2) * 16 + (bj & 15);
      int k = (bj >> 4) * 4 + (q & 3);
      if (vj && bqv[e]) {
        float dx = qpx[e] - jx, dy = qpy[e] - jy, dz = qpz[e] - jz;
        float d = sqrtf(dx * dx + dy * dy + dz * dz);
        float fi = d * 8.0f;
        int i = (int)fi; if (i > 382) i = 382;
        float fr2 = fi - (float)i;
        bf8x t0 = *(const bf8x*)&Tg[i][0];
        bf8x t1 = *(const bf8x*)&Tg[i + 1][0];
        #pragma unroll
        for (int h = 0; h < 8; ++h) {
          float u0 = b2f(t0.v[h]);
          float bv = u0 + fr2 * (b2f(t1.v[h]) - u0);
          Sbf[BUF][h][L][k] = __float2bfloat16(bv);
        }
      } else {
        bf16 s = __float2bfloat16(vj ? 0.f : -1e30f);
        #pragma unroll
        for (int h = 0; h < 8; ++h) Sbf[BUF][h][L][k] = s;
      }
    }
  };

  bf16x8 ck[2][2], cv[2][2];
  auto loadt = [&](int JT) {
    int k0 = JT * 32 + fr, k1 = k0 + 16;
    size_t r0 = (size_t)((k0 < n) ? k0 : 0) * 768;
    size_t r1 = (size_t)((k1 < n) ? k1 : 0) * 768;
    ck[0][0] = *(const bf16x8*)(Kb0 + r0); ck[0][1] = *(const bf16x8*)(Kb0 + r1);
    ck[1][0] = *(const bf16x8*)(Kb1 + r0); ck[1][1] = *(const bf16x8*)(Kb1 + r1);
    cv[0][0] = *(const bf16x8*)(Vb0 + JT * 32);
    cv[0][1] = *(const bf16x8*)(Vb0 + (size_t)16 * VT_LD + JT * 32);
    cv[1][0] = *(const bf16x8*)(Vb1 + JT * 32);
    cv[1][1] = *(const bf16x8*)(Vb1 + (size_t)16 * VT_LD + JT * 32);
  };

  __syncthreads();          // table ready
  produce(jt0, 0);
  __syncthreads();
  for (int jt = jt0; jt < jt1; ++jt) {
    int par = (jt - jt0) & 1;
    loadt(jt);                               // global loads: latency hidden by produce()
    if (jt + 1 < jt1) produce(jt + 1, par ^ 1);
    #pragma unroll
    for (int hh = 0; hh < 2; ++hh) {
      int h = w + 4 * hh;
      f32x4 z = {0.f, 0.f, 0.f, 0.f};
      f32x4 S0 = __builtin_amdgcn_mfma_f32_16x16x32_bf16(aq[hh], ck[hh][0], z, 0, 0, 0);
      f32x4 S1 = __builtin_amdgcn_mfma_f32_16x16x32_bf16(aq[hh], ck[hh][1], z, 0, 0, 0);
      bf8x bb = *(const bf8x*)&Sbf[par][h][l][0];
      #pragma unroll
      for (int k = 0; k < 8; ++k) {
        int jti = k >> 2, rr = k & 3;
        float s = (jti ? S1[rr] : S0[rr]) + b2f(bb.v[k]);
        float p = __expf(s);
        lacc[hh][rr] += p;
        Pt[w][fq * 4 + rr][jti * 16 + fr] = __float2bfloat16(p);
      }
      bf16x8 ap = *(const bf16x8*)&Pt[w][fr][fq * 8];
      Oa[hh][0] = __builtin_amdgcn_mfma_f32_16x16x32_bf16(ap, cv[hh][0], Oa[hh][0], 0, 0, 0);
      Oa[hh][1] = __builtin_amdgcn_mfma_f32_16x16x32_bf16(ap, cv[hh][1], Oa[hh][1], 0, 0, 0);
    }
    __syncthreads();
  }
  #pragma unroll
  for (int hh = 0; hh < 2; ++hh)
    #pragma unroll
    for (int rr = 0; rr < 4; ++rr) {
      #pragma unroll
      for (int m2 = 1; m2 <= 8; m2 <<= 1) lacc[hh][rr] += __shfl_xor(lacc[hh][rr], m2);
    }
  float* Opc = Op + (size_t)jc * N * 256;
  float* lpc = lp + (size_t)jc * N * 8;
  #pragma unroll
  for (int hh = 0; hh < 2; ++hh) {
    int h = w + 4 * hh;
    #pragma unroll
    for (int rr = 0; rr < 4; ++rr) {
      int row = q0 + fq * 4 + rr;
      if (row < n) {
        #pragma unroll
        for (int dh = 0; dh < 2; ++dh)
          Opc[(size_t)(off + row) * 256 + h * 32 + dh * 16 + fr] = Oa[hh][dh][rr];
        if (fr == 0) lpc[(size_t)(off + row) * 8 + h] = lacc[hh][rr];
      }
    }
  }
}

// ---------------- K4: combine j-partials + out-proj GEMM + residual + LN ----------------
__global__ __launch_bounds__(256) void k_out_ln(const float* __restrict__ Op,
                                                const float* __restrict__ lp,
                                                const bf16* __restrict__ Bt,
                                                const float* __restrict__ x,
                                                const float* __restrict__ gamma,
                                                const float* __restrict__ beta,
                                                float* __restrict__ out, int M) {
  __shared__ float ps[4][16], pss[4][16];
  int t = threadIdx.x, w = t >> 6, l = t & 63, fr = l & 15, fq = l >> 4;
  int m0 = blockIdx.x * 16;
  int arow = m0 + fr; if (arow > M - 1) arow = M - 1;
  const float* Op0 = Op;
  const float* Op1 = Op + (size_t)M * 256;
  float linv[8];
  {
    float4 a0 = *(const float4*)(lp + (size_t)arow * 8);
    float4 a1 = *(const float4*)(lp + (size_t)arow * 8 + 4);
    float4 b0 = *(const float4*)(lp + (size_t)(M + arow) * 8);
    float4 b1 = *(const float4*)(lp + (size_t)(M + arow) * 8 + 4);
    linv[0] = 1.f / (a0.x + b0.x); linv[1] = 1.f / (a0.y + b0.y);
    linv[2] = 1.f / (a0.z + b0.z); linv[3] = 1.f / (a0.w + b0.w);
    linv[4] = 1.f / (a1.x + b1.x); linv[5] = 1.f / (a1.y + b1.y);
    linv[6] = 1.f / (a1.z + b1.z); linv[7] = 1.f / (a1.w + b1.w);
  }
  bf16x8 af[8];
  #pragma unroll
  for (int kt = 0; kt < 8; ++kt) {  // head h == kt (32 d per head)
    size_t o = (size_t)arow * 256 + kt * 32 + fq * 8;
    float4 u0 = *(const float4*)(Op0 + o), v0 = *(const float4*)(Op0 + o + 4);
    float4 u1 = *(const float4*)(Op1 + o), v1 = *(const float4*)(Op1 + o + 4);
    float li = linv[kt];
    __align__(16) bf16 tmp[8];
    tmp[0] = __float2bfloat16((u0.x + u1.x) * li);
    tmp[1] = __float2bfloat16((u0.y + u1.y) * li);
    tmp[2] = __float2bfloat16((u0.z + u1.z) * li);
    tmp[3] = __float2bfloat16((u0.w + u1.w) * li);
    tmp[4] = __float2bfloat16((v0.x + v1.x) * li);
    tmp[5] = __float2bfloat16((v0.y + v1.y) * li);
    tmp[6] = __float2bfloat16((v0.z + v1.z) * li);
    tmp[7] = __float2bfloat16((v0.w + v1.w) * li);
    af[kt] = *(const bf16x8*)tmp;
  }
  f32x4 acc[4];
  #pragma unroll
  for (int nt = 0; nt < 4; ++nt) {
    acc[nt] = (f32x4){0.f, 0.f, 0.f, 0.f};
    int brow = w * 64 + nt * 16 + fr;
    #pragma unroll
    for (int kt = 0; kt < 8; ++kt) {
      bf16x8 bf_ = *(const bf16x8*)(Bt + (size_t)brow * 256 + kt * 32 + fq * 8);
      acc[nt] = __builtin_amdgcn_mfma_f32_16x16x32_bf16(af[kt], bf_, acc[nt], 0, 0, 0);
    }
  }
  float y[4][4];
  #pragma unroll
  for (int rr = 0; rr < 4; ++rr) {
    int row = m0 + fq * 4 + rr;
    int rc = (row < M) ? row : (M - 1);
    float s = 0.f, ss = 0.f;
    #pragma unroll
    for (int nt = 0; nt < 4; ++nt) {
      float v = acc[nt][rr] + x[(size_t)rc * 256 + w * 64 + nt * 16 + fr];
      y[rr][nt] = v; s += v; ss += v * v;
    }
    #pragma unroll
    for (int m2 = 1; m2 <= 8; m2 <<= 1) { s += __shfl_xor(s, m2); ss += __shfl_xor(ss, m2); }
    if (fr == 0) { ps[w][fq * 4 + rr] = s; pss[w][fq * 4 + rr] = ss; }
  }
  __syncthreads();
  #pragma unroll
  for (int rr = 0; rr < 4; ++rr) {
    int row = m0 + fq * 4 + rr;
    int ri = fq * 4 + rr;
    float s = ps[0][ri] + ps[1][ri] + ps[2][ri] + ps[3][ri];
    float ss = pss[0][ri] + pss[1][ri] + pss[2][ri] + pss[3][ri];
    float mean = s * (1.f / 256.f);
    float var = ss * (1.f / 256.f) - mean * mean;
    float rstd = rsqrtf(var + 1e-5f);
    if (row < M) {
      #pragma unroll
      for (int nt = 0; nt < 4; ++nt) {
        int col = w * 64 + nt * 16 + fr;
        out[(size_t)row * 256 + col] = gamma[col] * (y[rr][nt] - mean) * rstd + beta[col];
      }
    }
  }
}

extern "C" void kernel_launch(void* const* d_in, const int* in_sizes, int n_in,
                              void* d_out, int out_size, void* d_ws, size_t ws_size,
                              hipStream_t stream) {
  (void)n_in; (void)out_size; (void)ws_size;
  const float* x     = (const float*)d_in[0];
  const float* pos   = (const float*)d_in[1];
  const int*   batch = (const int*)d_in[2];
  const float* Wqkv  = (const float*)d_in[3];
  const float* Wout  = (const float*)d_in[4];
  const float* freqs = (const float*)d_in[5];
  const float* Wrope = (const float*)d_in[6];
  const float* gamma = (const float*)d_in[7];
  const float* beta  = (const float*)d_in[8];
  float* out = (float*)d_out;

  int N = in_sizes[0] / 256;  // 6137

  char* base = (char*)d_ws;
  int*   offs   = (int*)base;                   // @0
  bf16*  QKVb   = (bf16*)(base + 1024);         // N*768*2  = 9,426,432
  bf16*  VT     = (bf16*)(base + 9427456);      // 4,194,304
  bf16*  Wqkv_t = (bf16*)(base + 13621760);     // 393,216
  bf16*  Wout_t = (bf16*)(base + 14014976);     // 131,072
  float* Op     = (float*)(base + 14146048);    // 2 x N*256*4 = 12,568,576
  float* lp     = (float*)(base + 26714624);    // 2 x N*8*4

  int MBm = (N + 63) / 64;  // 96
  k_pre<<<65, 256, 0, stream>>>(Wqkv, Wout, batch, Wqkv_t, Wout_t, offs, N);
  k_gemm<<<dim3(MBm, 4), 256, 0, stream>>>(x, Wqkv_t, batch, offs, QKVb, VT, N);
  k_attn<<<dim3(32, NGRAPH, 2), 256, 0, stream>>>(pos, freqs, Wrope, QKVb, VT, offs, Op, lp, N);
  k_out_ln<<<(N + 15) / 16, 256, 0, stream>>>(Op, lp, Wout_t, x, gamma, beta, out, N);
}